// Round 7
// baseline (158.450 us; speedup 1.0000x reference)
//
#include <hip/hip_runtime.h>
#include <cstdint>
#include <cstddef>

// Problem constants
#define B_    16
#define S_    1024
#define D_    768
#define NS_   256
#define V_    128
#define C_    6
#define R_    512
#define REL_  97
#define HID_  384
#define DIS_  20
#define KD_   768    // K for both hoisted GEMMs (= D_)
#define N2P_  128    // gemm2 padded N

typedef unsigned short ushort_t;
typedef unsigned int   u32;
typedef short bf16x4 __attribute__((ext_vector_type(4)));
typedef short bf16x8 __attribute__((ext_vector_type(8)));
typedef float f32x4  __attribute__((ext_vector_type(4)));
typedef float f32x16 __attribute__((ext_vector_type(16)));

__device__ __forceinline__ float bf2f(short s) {
    return __uint_as_float(((unsigned int)(unsigned short)s) << 16);
}
__device__ __forceinline__ short f2bf(float x) {   // RNE
    union { float f; unsigned int u; } c; c.f = x;
    unsigned int r = (c.u + 0x7fffu + ((c.u >> 16) & 1u)) >> 16;
    return (short)(unsigned short)r;
}

// async global->LDS, 16 B per lane; LDS dest = wave-uniform base + lane*16
typedef const __attribute__((address_space(1))) u32* gas_t;
typedef __attribute__((address_space(3))) u32*       las_t;
__device__ __forceinline__ void dma16(const void* g, void* l) {
    __builtin_amdgcn_global_load_lds((gas_t)g, (las_t)l, 16, 0, 0);
}

// ---------------------------------------------------------------------------
// Kernel 1 (fused vertex + repacks), 192 threads:
//  blocks [0,2048):      vertex mean with INLINE span max-pool. span_emb is
//                        never materialized: for each of the <=6 referenced
//                        spans, gather rows, max-pool in f32, round to bf16
//                        (same rounding point as the old 2-kernel path ->
//                        bit-identical), accumulate, divide, write vembB.
//  blocks [2048,2432):   W1 head|tail repack -> W1HT   (384 blocks)
//  blocks [2432,2624):   W1 prod repack     -> W1P    (192 blocks)
//  blocks [2624,2656):   W2 -> W2T (n-padded)          (32 blocks)
//  blocks [2656,2736):   dis projection tables (f32 exact)  (80 blocks)
// ---------------------------------------------------------------------------
__global__ __launch_bounds__(192) void fused_prep_kernel(
    const float* __restrict__ sr, const int* __restrict__ spans,
    const int* __restrict__ vidx, const int* __restrict__ vmask,
    const float* __restrict__ W1, const float* __restrict__ W2,
    const float* __restrict__ dis,
    ushort_t* __restrict__ vembB, ushort_t* __restrict__ W1HT,
    ushort_t* __restrict__ W1P, ushort_t* __restrict__ W2T,
    float* __restrict__ disH, float* __restrict__ disT)
{
    int blk = blockIdx.x;
    int tid = threadIdx.x;
    if (blk < 2048) {                        // fused vertex mean
        int bv = blk;
        int b  = bv >> 7;                    // V = 128
        const int* vi = vidx  + bv * C_;
        const int* vm = vmask + bv * C_;
        int col = tid * 4;
        float s[4] = {0.f, 0.f, 0.f, 0.f};
        float cnt = 0.f;
#pragma unroll
        for (int c = 0; c < C_; ++c) {
            int mc = vm[c];
            cnt += (float)mc;
            if (mc) {                        // block-uniform branch
                int sn    = b * NS_ + vi[c];
                int start = spans[2 * sn];
                int end   = spans[2 * sn + 1];
                int w     = end - start;     // 0..7, block-uniform
                const float* base = sr + ((size_t)b * S_ + start) * D_ + col;
                f32x4 x[8];
                x[0] = *(const f32x4*)base;
                switch (w) {                 // block-uniform fallthrough
                case 7: x[7] = *(const f32x4*)(base + 7 * D_); [[fallthrough]];
                case 6: x[6] = *(const f32x4*)(base + 6 * D_); [[fallthrough]];
                case 5: x[5] = *(const f32x4*)(base + 5 * D_); [[fallthrough]];
                case 4: x[4] = *(const f32x4*)(base + 4 * D_); [[fallthrough]];
                case 3: x[3] = *(const f32x4*)(base + 3 * D_); [[fallthrough]];
                case 2: x[2] = *(const f32x4*)(base + 2 * D_); [[fallthrough]];
                case 1: x[1] = *(const f32x4*)(base + 1 * D_); break;
                default: break;
                }
                f32x4 m = x[0];
#pragma unroll
                for (int j = 1; j < 8; ++j)
                    if (j <= w) {
#pragma unroll
                        for (int q = 0; q < 4; ++q) m[q] = fmaxf(m[q], x[j][q]);
                    }
                // round through bf16 exactly like the old span_emb path
#pragma unroll
                for (int q = 0; q < 4; ++q) s[q] += bf2f(f2bf(m[q]));
            }
        }
        float inv = 1.f / fmaxf(cnt, 1.f);
        bf16x4 o;
#pragma unroll
        for (int q = 0; q < 4; ++q) o[q] = f2bf(s[q] * inv);
        *(bf16x4*)(vembB + (size_t)bv * D_ + col) = o;
    } else if (blk < 2432) {                 // W1HT: 384 blocks
        int flat = (blk - 2048) * 192 + tid;
        int nn   = flat & 63;
        int kg   = (flat >> 6) & 7;
        int itnt = flat >> 9;                // it*12 + nt, 0..143
        int it   = itnt / 12;
        int nt   = itnt - it * 12;
        bf16x8 p;
#pragma unroll
        for (int j = 0; j < 8; ++j) {
            int k = it * 64 + kg * 8 + j;
            int n = nt * 64 + nn;
            float v = (n < HID_) ? W1[(size_t)k * HID_ + n]
                                 : W1[(size_t)(788 + k) * HID_ + (n - HID_)];
            p[j] = f2bf(v);
        }
        *(bf16x8*)(W1HT + ((size_t)itnt * 8 + kg) * 512 + nn * 8) = p;
    } else if (blk < 2624) {                 // W1P: 192 blocks
        int flat = (blk - 2432) * 192 + tid;
        int nn   = flat & 63;
        int kg   = (flat >> 6) & 7;
        int itnt = flat >> 9;                // it*6 + nt, 0..71
        int it   = itnt / 6;
        int nt   = itnt - it * 6;
        bf16x8 p;
#pragma unroll
        for (int j = 0; j < 8; ++j) {
            int k = it * 64 + kg * 8 + j;
            int n = nt * 64 + nn;
            p[j] = f2bf(W1[(size_t)(1576 + k) * HID_ + n]);
        }
        *(bf16x8*)(W1P + ((size_t)itnt * 8 + kg) * 512 + nn * 8) = p;
    } else if (blk < 2656) {                 // W2T: 32 blocks
        int g  = (blk - 2624) * 192 + tid;   // 0..6143
        int n  = g / 48;
        int k0 = (g - n * 48) * 8;
        bf16x8 p;
#pragma unroll
        for (int j = 0; j < 8; ++j) {
            float v = (n < REL_) ? W2[(size_t)(k0 + j) * REL_ + n] : 0.f;
            p[j] = f2bf(v);
        }
        *(bf16x8*)(W2T + (size_t)n * HID_ + k0) = p;
    } else {                                 // dis tables: 80 blocks
        int g   = (blk - 2656) * 192 + tid;
        int sel = g >= 7680;
        int gg  = sel ? g - 7680 : g;
        int i   = gg / HID_;
        int n   = gg - i * HID_;
        int rb  = sel ? 1556 : 768;
        float a = 0.f;
#pragma unroll
        for (int j = 0; j < DIS_; ++j)
            a += dis[i * DIS_ + j] * W1[(size_t)(rb + j) * HID_ + n];
        (sel ? disT : disH)[i * HID_ + n] = a;
    }
}

// ---------------------------------------------------------------------------
// Kernel 2 (GEMM C): vproj = vembB(2048x768) @ W1HT(768x768), f32 (verbatim).
// ---------------------------------------------------------------------------
__global__ __launch_bounds__(256, 3) void gemmc_kernel(
    const ushort_t* __restrict__ vembB, const ushort_t* __restrict__ W1HT,
    float* __restrict__ vproj)
{
    __shared__ ushort_t Abuf[2][64][64];
    __shared__ ushort_t Bbuf[2][8][64][8];

    int tid  = threadIdx.x;
    int wv   = tid >> 6;
    int lane = tid & 63;
    int m0   = blockIdx.x * 64;
    int nt   = blockIdx.y;
    int n0   = nt * 64;

    int rr  = lane >> 3;
    int sl  = lane & 7;
    int gsw = (sl - rr) & 7;

    const ushort_t* asrc[2];
#pragma unroll
    for (int gi = 0; gi < 2; ++gi)
        asrc[gi] = vembB + (size_t)(m0 + wv * 16 + gi * 8 + rr) * KD_ + gsw * 8;

    auto stage = [&](int bf, int it) {
#pragma unroll
        for (int gi = 0; gi < 2; ++gi)
            dma16(asrc[gi] + it * 64, &Abuf[bf][wv * 16 + gi * 8][0]);
        const ushort_t* bbase = W1HT + ((size_t)it * 12 + nt) * 4096;
#pragma unroll
        for (int q = 0; q < 2; ++q) {
            int p = wv * 2 + q;
            dma16(bbase + (size_t)p * 512 + lane * 8, &Bbuf[bf][p][0][0]);
        }
    };

    int half = lane >> 5;
    int lrow = lane & 31;
    int wm   = (wv & 1) * 32;
    int wn   = (wv >> 1) * 32;

    f32x16 acc;
#pragma unroll
    for (int r = 0; r < 16; ++r) acc[r] = 0.f;

    stage(0, 0);
    for (int it = 0; it < 12; ++it) {
        int bf = it & 1;
        __syncthreads();
        if (it + 1 < 12) stage(bf ^ 1, it + 1);
#pragma unroll
        for (int s = 0; s < 4; ++s) {
            int kg   = s * 2 + half;
            int slot = ((kg + lrow) & 7) * 8;
            bf16x8 a = *(bf16x8*)&Abuf[bf][wm + lrow][slot];
            bf16x8 b = *(bf16x8*)&Bbuf[bf][kg][wn + lrow][0];
            acc = __builtin_amdgcn_mfma_f32_32x32x16_bf16(a, b, acc, 0, 0, 0);
        }
    }

    int col = n0 + wn + lrow;
#pragma unroll
    for (int r = 0; r < 16; ++r) {
        int row = m0 + wm + (r & 3) + 8 * (r >> 2) + 4 * half;
        vproj[(size_t)row * KD_ + col] = acc[r];
    }
}

// ---------------------------------------------------------------------------
// Kernel 3 (GEMM D): pair-product GEMM + additive epilogue.
// (verbatim R3-verified version: 128x6 grid, 256 threads, 3 blocks/CU)
// ---------------------------------------------------------------------------
__global__ __launch_bounds__(256, 3) void gemmd_kernel(
    const ushort_t* __restrict__ vembB, const int* __restrict__ ht,
    const int* __restrict__ dht, const int* __restrict__ dth,
    const ushort_t* __restrict__ W1P, const float* __restrict__ vproj,
    const float* __restrict__ disH, const float* __restrict__ disT,
    ushort_t* __restrict__ hidden)
{
    __shared__ ushort_t Abuf[2][64][64];
    __shared__ ushort_t Bbuf[2][8][64][8];
    __shared__ int hI[64], tI[64], dhI[64], dtI[64];

    int tid  = threadIdx.x;
    int wv   = tid >> 6;
    int lane = tid & 63;
    int m0   = blockIdx.x * 64;
    int nt   = blockIdx.y;
    int n0   = nt * 64;

    int rr  = lane >> 3;
    int sl  = lane & 7;
    int gsw = (sl - rr) & 7;

    if (tid < 64) {
        int g = m0 + tid;
        int b = g >> 9;                      // R = 512
        hI[tid]  = b * V_ + ht[2 * g];
        tI[tid]  = b * V_ + ht[2 * g + 1];
        dhI[tid] = dht[g];
        dtI[tid] = dth[g];
    }

    int hoff[2], toff[2];
#pragma unroll
    for (int gi = 0; gi < 2; ++gi) {
        int g = m0 + wv * 16 + gi * 8 + rr;
        int b = g >> 9;
        hoff[gi] = (b * V_ + ht[2 * g])     * KD_;
        toff[gi] = (b * V_ + ht[2 * g + 1]) * KD_;
    }

    auto stage = [&](int bf, int it) {
        int kk = it * 64 + gsw * 8;
#pragma unroll
        for (int gi = 0; gi < 2; ++gi) {
            bf16x8 h = *(const bf16x8*)(vembB + hoff[gi] + kk);
            bf16x8 t = *(const bf16x8*)(vembB + toff[gi] + kk);
            bf16x8 p;
#pragma unroll
            for (int j = 0; j < 8; ++j) p[j] = f2bf(bf2f(h[j]) * bf2f(t[j]));
            *(bf16x8*)&Abuf[bf][wv * 16 + gi * 8 + rr][sl * 8] = p;
        }
        const ushort_t* bbase = W1P + ((size_t)it * 6 + nt) * 4096;
#pragma unroll
        for (int q = 0; q < 2; ++q) {
            int p = wv * 2 + q;
            dma16(bbase + (size_t)p * 512 + lane * 8, &Bbuf[bf][p][0][0]);
        }
    };

    int half = lane >> 5;
    int lrow = lane & 31;
    int wm   = (wv & 1) * 32;
    int wn   = (wv >> 1) * 32;

    f32x16 acc;
#pragma unroll
    for (int r = 0; r < 16; ++r) acc[r] = 0.f;

    stage(0, 0);
    for (int it = 0; it < 12; ++it) {
        int bf = it & 1;
        __syncthreads();
        if (it + 1 < 12) stage(bf ^ 1, it + 1);
#pragma unroll
        for (int s = 0; s < 4; ++s) {
            int kg   = s * 2 + half;
            int slot = ((kg + lrow) & 7) * 8;
            bf16x8 a = *(bf16x8*)&Abuf[bf][wm + lrow][slot];
            bf16x8 b = *(bf16x8*)&Bbuf[bf][kg][wn + lrow][0];
            acc = __builtin_amdgcn_mfma_f32_32x32x16_bf16(a, b, acc, 0, 0, 0);
        }
    }

    int col = n0 + wn + lrow;
#pragma unroll
    for (int r = 0; r < 16; ++r) {
        int rl = wm + (r & 3) + 8 * (r >> 2) + 4 * half;
        float v = acc[r]
                + vproj[(size_t)hI[rl] * KD_ + col]
                + vproj[(size_t)tI[rl] * KD_ + HID_ + col]
                + disH[dhI[rl] * HID_ + col]
                + disT[dtI[rl] * HID_ + col];
        hidden[(size_t)(m0 + rl) * HID_ + col] = (ushort_t)f2bf(fmaxf(v, 0.f));
    }
}

// ---------------------------------------------------------------------------
// Kernel 4: MFMA GEMM2 + bias (verbatim verified).
// ---------------------------------------------------------------------------
__global__ __launch_bounds__(256) void gemm2_kernel(
    const ushort_t* __restrict__ hidden, const ushort_t* __restrict__ W2T,
    const float* __restrict__ b2, float* __restrict__ out)
{
    __shared__ ushort_t As[32][72];
    __shared__ ushort_t Bs[128][72];

    int m0  = blockIdx.x * 32;
    int tid = threadIdx.x;

    int arow = tid >> 3;             // 0..31
    int akk  = (tid & 7) * 8;

    bf16x8 pA; bf16x8 pB[4];
    auto loadAB = [&](int k0) {
        pA = *(const bf16x8*)(hidden + (size_t)(m0 + arow) * HID_ + k0 + akk);
#pragma unroll
        for (int e = 0; e < 4; ++e)
            pB[e] = *(const bf16x8*)(W2T + (size_t)(arow + e * 32) * HID_ + k0 + akk);
    };

    int w    = tid >> 6;
    int lane = tid & 63;
    int wm = (w & 1) * 16;
    int wn = (w >> 1) * 64;
    int lr = lane & 15, lq = lane >> 4;

    f32x4 acc[4];
#pragma unroll
    for (int e = 0; e < 4; ++e) acc[e] = (f32x4){0.f, 0.f, 0.f, 0.f};

    loadAB(0);
    for (int k0 = 0; k0 < HID_; k0 += 64) {
        __syncthreads();
        *(bf16x8*)&As[arow][akk] = pA;
#pragma unroll
        for (int e = 0; e < 4; ++e)
            *(bf16x8*)&Bs[arow + e * 32][akk] = pB[e];
        __syncthreads();
        if (k0 + 64 < HID_) loadAB(k0 + 64);
#pragma unroll
        for (int ks = 0; ks < 2; ++ks) {
            int kb = ks * 32 + lq * 8;
            bf16x8 a = *(bf16x8*)&As[wm + lr][kb];
#pragma unroll
            for (int nf = 0; nf < 4; ++nf) {
                bf16x8 bb = *(bf16x8*)&Bs[wn + nf * 16 + lr][kb];
                acc[nf] = __builtin_amdgcn_mfma_f32_16x16x32_bf16(a, bb, acc[nf], 0, 0, 0);
            }
        }
    }

    int grow = m0 + wm + lq * 4;
#pragma unroll
    for (int nf = 0; nf < 4; ++nf) {
        int col = wn + nf * 16 + lr;
        if (col < REL_) {
            float bias = b2[col];
#pragma unroll
            for (int r = 0; r < 4; ++r)
                out[(size_t)(grow + r) * REL_ + col] = acc[nf][r] + bias;
        }
    }
}

// ---------------------------------------------------------------------------
extern "C" void kernel_launch(void* const* d_in, const int* in_sizes, int n_in,
                              void* d_out, int out_size, void* d_ws, size_t ws_size,
                              hipStream_t stream)
{
    const float* sr    = (const float*)d_in[0];
    const int*   spans = (const int*)  d_in[1];
    const int*   vidx  = (const int*)  d_in[3];
    const int*   vmask = (const int*)  d_in[4];
    const int*   ht    = (const int*)  d_in[5];
    const int*   dht   = (const int*)  d_in[7];
    const int*   dth   = (const int*)  d_in[8];
    const float* dis   = (const float*)d_in[9];
    const float* W1    = (const float*)d_in[10];
    const float* W2    = (const float*)d_in[11];
    const float* b2    = (const float*)d_in[12];
    float* out = (float*)d_out;

    // ws layout (bf16 regions first, then f32); span_emb no longer exists:
    ushort_t* vembB  = (ushort_t*)d_ws;                       // 2048*768
    ushort_t* W1HT   = vembB + (size_t)B_ * V_ * D_;          // 144*4096
    ushort_t* W1P    = W1HT + (size_t)144 * 4096;             // 72*4096
    ushort_t* W2T    = W1P + (size_t)72 * 4096;               // 128*384
    ushort_t* hidden = W2T + (size_t)N2P_ * HID_;             // 8192*384
    float* vproj = (float*)(hidden + (size_t)B_ * R_ * HID_); // 2048*768 f32
    float* disH  = vproj + (size_t)B_ * V_ * KD_;             // 20*384 f32
    float* disT  = disH + (size_t)DIS_ * HID_;                // 20*384 f32

    fused_prep_kernel<<<2736, 192, 0, stream>>>(
        sr, spans, vidx, vmask, W1, W2, dis,
        vembB, W1HT, W1P, W2T, disH, disT);
    gemmc_kernel<<<dim3(32, 12), 256, 0, stream>>>(vembB, W1HT, vproj);
    gemmd_kernel<<<dim3(128, 6), 256, 0, stream>>>(
        vembB, ht, dht, dth, W1P, vproj, disH, disT, hidden);
    gemm2_kernel<<<(B_ * R_) / 32, 256, 0, stream>>>(hidden, W2T, b2, out);
}

// Round 8
// 153.033 us; speedup vs baseline: 1.0354x; 1.0354x over previous
//
#include <hip/hip_runtime.h>
#include <cstdint>
#include <cstddef>

// Problem constants
#define B_    16
#define S_    1024
#define D_    768
#define NS_   256
#define V_    128
#define C_    6
#define R_    512
#define REL_  97
#define HID_  384
#define DIS_  20
#define KD_   768    // K for both hoisted GEMMs (= D_)
#define N2P_  128    // gemm2 padded N

typedef unsigned short ushort_t;
typedef unsigned int   u32;
typedef short bf16x4 __attribute__((ext_vector_type(4)));
typedef short bf16x8 __attribute__((ext_vector_type(8)));
typedef float f32x4  __attribute__((ext_vector_type(4)));
typedef float f32x16 __attribute__((ext_vector_type(16)));

__device__ __forceinline__ float bf2f(short s) {
    return __uint_as_float(((unsigned int)(unsigned short)s) << 16);
}
__device__ __forceinline__ short f2bf(float x) {   // RNE
    union { float f; unsigned int u; } c; c.f = x;
    unsigned int r = (c.u + 0x7fffu + ((c.u >> 16) & 1u)) >> 16;
    return (short)(unsigned short)r;
}

// async global->LDS, 16 B per lane; LDS dest = wave-uniform base + lane*16
typedef const __attribute__((address_space(1))) u32* gas_t;
typedef __attribute__((address_space(3))) u32*       las_t;
__device__ __forceinline__ void dma16(const void* g, void* l) {
    __builtin_amdgcn_global_load_lds((gas_t)g, (las_t)l, 16, 0, 0);
}

// ---------------------------------------------------------------------------
// Kernel 1 (prep), 192 threads: span max-pool, W1/W2 repacks, dis tables.
// (verbatim R3-verified)
// ---------------------------------------------------------------------------
__global__ __launch_bounds__(192) void prep_kernel(
    const float* __restrict__ sr, const int* __restrict__ spans,
    const float* __restrict__ W1, const float* __restrict__ W2,
    const float* __restrict__ dis,
    ushort_t* __restrict__ span_emb, ushort_t* __restrict__ W1HT,
    ushort_t* __restrict__ W1P, ushort_t* __restrict__ W2T,
    float* __restrict__ disH, float* __restrict__ disT)
{
    int blk = blockIdx.x;
    int tid = threadIdx.x;
    if (blk < 4096) {
        int bn    = blk;
        int b     = bn >> 8;                 // NS = 256
        int start = spans[2 * bn];
        int end   = spans[2 * bn + 1];
        int w     = end - start;             // 0..7, block-uniform
        const float* base = sr + ((size_t)b * S_ + start) * D_ + tid * 4;
        f32x4 x[8];
        x[0] = *(const f32x4*)base;
        switch (w) {                         // block-uniform fallthrough
        case 7: x[7] = *(const f32x4*)(base + 7 * D_); [[fallthrough]];
        case 6: x[6] = *(const f32x4*)(base + 6 * D_); [[fallthrough]];
        case 5: x[5] = *(const f32x4*)(base + 5 * D_); [[fallthrough]];
        case 4: x[4] = *(const f32x4*)(base + 4 * D_); [[fallthrough]];
        case 3: x[3] = *(const f32x4*)(base + 3 * D_); [[fallthrough]];
        case 2: x[2] = *(const f32x4*)(base + 2 * D_); [[fallthrough]];
        case 1: x[1] = *(const f32x4*)(base + 1 * D_); break;
        default: break;
        }
        f32x4 m = x[0];
#pragma unroll
        for (int j = 1; j < 8; ++j)
            if (j <= w) {
#pragma unroll
                for (int c = 0; c < 4; ++c) m[c] = fmaxf(m[c], x[j][c]);
            }
        bf16x4 o;
#pragma unroll
        for (int c = 0; c < 4; ++c) o[c] = f2bf(m[c]);
        *(bf16x4*)(span_emb + (size_t)bn * D_ + tid * 4) = o;
    } else if (blk < 4480) {                 // W1HT: 384 blocks
        int flat = (blk - 4096) * 192 + tid;
        int nn   = flat & 63;
        int kg   = (flat >> 6) & 7;
        int itnt = flat >> 9;                // it*12 + nt, 0..143
        int it   = itnt / 12;
        int nt   = itnt - it * 12;
        bf16x8 p;
#pragma unroll
        for (int j = 0; j < 8; ++j) {
            int k = it * 64 + kg * 8 + j;
            int n = nt * 64 + nn;
            float v = (n < HID_) ? W1[(size_t)k * HID_ + n]
                                 : W1[(size_t)(788 + k) * HID_ + (n - HID_)];
            p[j] = f2bf(v);
        }
        *(bf16x8*)(W1HT + ((size_t)itnt * 8 + kg) * 512 + nn * 8) = p;
    } else if (blk < 4672) {                 // W1P: 192 blocks
        int flat = (blk - 4480) * 192 + tid;
        int nn   = flat & 63;
        int kg   = (flat >> 6) & 7;
        int itnt = flat >> 9;                // it*6 + nt, 0..71
        int it   = itnt / 6;
        int nt   = itnt - it * 6;
        bf16x8 p;
#pragma unroll
        for (int j = 0; j < 8; ++j) {
            int k = it * 64 + kg * 8 + j;
            int n = nt * 64 + nn;
            p[j] = f2bf(W1[(size_t)(1576 + k) * HID_ + n]);
        }
        *(bf16x8*)(W1P + ((size_t)itnt * 8 + kg) * 512 + nn * 8) = p;
    } else if (blk < 4704) {                 // W2T: 32 blocks
        int g  = (blk - 4672) * 192 + tid;   // 0..6143
        int n  = g / 48;
        int k0 = (g - n * 48) * 8;
        bf16x8 p;
#pragma unroll
        for (int j = 0; j < 8; ++j) {
            float v = (n < REL_) ? W2[(size_t)(k0 + j) * REL_ + n] : 0.f;
            p[j] = f2bf(v);
        }
        *(bf16x8*)(W2T + (size_t)n * HID_ + k0) = p;
    } else {                                 // dis tables: 80 blocks
        int g   = (blk - 4704) * 192 + tid;
        int sel = g >= 7680;
        int gg  = sel ? g - 7680 : g;
        int i   = gg / HID_;
        int n   = gg - i * HID_;
        int rb  = sel ? 1556 : 768;
        float a = 0.f;
#pragma unroll
        for (int j = 0; j < DIS_; ++j)
            a += dis[i * DIS_ + j] * W1[(size_t)(rb + j) * HID_ + n];
        (sel ? disT : disH)[i * HID_ + n] = a;
    }
}

// ---------------------------------------------------------------------------
// Kernel 2: vertex mean (verbatim R3-verified).
// ---------------------------------------------------------------------------
__global__ __launch_bounds__(192) void vertex_kernel(
    const ushort_t* __restrict__ span_emb, const int* __restrict__ vidx,
    const int* __restrict__ vmask, ushort_t* __restrict__ vembB)
{
    int bv = blockIdx.x;
    int b  = bv >> 7;                // V = 128
    const int* vi = vidx  + bv * C_;
    const int* vm = vmask + bv * C_;
    int   idxs[C_];
    float ms[C_];
    float cnt = 0.f;
#pragma unroll
    for (int c = 0; c < C_; ++c) {
        idxs[c] = vi[c];
        ms[c]   = (float)vm[c];
        cnt    += ms[c];
    }
    float inv = 1.f / fmaxf(cnt, 1.f);
    int col = threadIdx.x * 4;
    float s[4] = {0.f, 0.f, 0.f, 0.f};
#pragma unroll
    for (int c = 0; c < C_; ++c) {
        if (ms[c] != 0.f) {
            bf16x4 x = *(const bf16x4*)(span_emb +
                        ((size_t)(b * NS_ + idxs[c])) * D_ + col);
#pragma unroll
            for (int q = 0; q < 4; ++q) s[q] += bf2f(x[q]);
        }
    }
    bf16x4 o;
#pragma unroll
    for (int q = 0; q < 4; ++q) o[q] = f2bf(s[q] * inv);
    *(bf16x4*)(vembB + (size_t)bv * D_ + col) = o;
}

// ---------------------------------------------------------------------------
// Kernel 3 (GEMM C, re-tiled): vproj = vembB(2048x768) @ W1HT(768x768), f32.
// BM=32 x BN=64, 128 threads (2 waves side-by-side, each 32x32), 24 KB LDS
// -> 6 blocks/CU capacity. Grid 64 x 12 = 768 blocks. Same swizzle/layout
// math as the verified 4-wave version; only the tiling changed.
// ---------------------------------------------------------------------------
__global__ __launch_bounds__(128, 3) void gemmc_kernel(
    const ushort_t* __restrict__ vembB, const ushort_t* __restrict__ W1HT,
    float* __restrict__ vproj)
{
    __shared__ ushort_t Abuf[2][32][64];     // 8 KB (swizzled slots)
    __shared__ ushort_t Bbuf[2][8][64][8];   // 16 KB (granule planes)

    int tid  = threadIdx.x;
    int wv   = tid >> 6;                     // 0..1
    int lane = tid & 63;
    int m0   = blockIdx.x * 32;
    int nt   = blockIdx.y;                   // 0..11
    int n0   = nt * 64;

    int rr  = lane >> 3;
    int sl  = lane & 7;
    int gsw = (sl - rr) & 7;

    const ushort_t* asrc[2];
#pragma unroll
    for (int gi = 0; gi < 2; ++gi)
        asrc[gi] = vembB + (size_t)(m0 + wv * 16 + gi * 8 + rr) * KD_ + gsw * 8;

    auto stage = [&](int bf, int it) {
#pragma unroll
        for (int gi = 0; gi < 2; ++gi)
            dma16(asrc[gi] + it * 64, &Abuf[bf][wv * 16 + gi * 8][0]);
        const ushort_t* bbase = W1HT + ((size_t)it * 12 + nt) * 4096;
#pragma unroll
        for (int q = 0; q < 4; ++q) {
            int p = wv * 4 + q;
            dma16(bbase + (size_t)p * 512 + lane * 8, &Bbuf[bf][p][0][0]);
        }
    };

    int half = lane >> 5;
    int lrow = lane & 31;
    int wn   = wv * 32;

    f32x16 acc;
#pragma unroll
    for (int r = 0; r < 16; ++r) acc[r] = 0.f;

    stage(0, 0);
    for (int it = 0; it < 12; ++it) {
        int bf = it & 1;
        __syncthreads();
        if (it + 1 < 12) stage(bf ^ 1, it + 1);
#pragma unroll
        for (int s = 0; s < 4; ++s) {
            int kg   = s * 2 + half;
            int slot = ((kg + lrow) & 7) * 8;
            bf16x8 a = *(bf16x8*)&Abuf[bf][lrow][slot];
            bf16x8 b = *(bf16x8*)&Bbuf[bf][kg][wn + lrow][0];
            acc = __builtin_amdgcn_mfma_f32_32x32x16_bf16(a, b, acc, 0, 0, 0);
        }
    }

    // C/D 32x32 layout: col=lane&31, row=(reg&3)+8*(reg>>2)+4*(lane>>5)
    int col = n0 + wn + lrow;
#pragma unroll
    for (int r = 0; r < 16; ++r) {
        int row = m0 + (r & 3) + 8 * (r >> 2) + 4 * half;
        vproj[(size_t)row * KD_ + col] = acc[r];
    }
}

// ---------------------------------------------------------------------------
// Kernel 4 (GEMM D, re-tiled): pair-product GEMM + additive epilogue.
// BM=32 x BN=64, 128 threads (2 waves), ~24.5 KB LDS -> 6 blocks/CU.
// Grid 256 x 6 = 1536 blocks (nt=6 kept -> gather A-traffic unchanged vs R3;
// only cheap contiguous B-plane traffic doubles).
// ---------------------------------------------------------------------------
__global__ __launch_bounds__(128, 3) void gemmd_kernel(
    const ushort_t* __restrict__ vembB, const int* __restrict__ ht,
    const int* __restrict__ dht, const int* __restrict__ dth,
    const ushort_t* __restrict__ W1P, const float* __restrict__ vproj,
    const float* __restrict__ disH, const float* __restrict__ disT,
    ushort_t* __restrict__ hidden)
{
    __shared__ ushort_t Abuf[2][32][64];     // 8 KB (swizzled slots)
    __shared__ ushort_t Bbuf[2][8][64][8];   // 16 KB (granule planes)
    __shared__ int hI[32], tI[32], dhI[32], dtI[32];

    int tid  = threadIdx.x;
    int wv   = tid >> 6;                     // 0..1
    int lane = tid & 63;
    int m0   = blockIdx.x * 32;
    int nt   = blockIdx.y;                   // 0..5
    int n0   = nt * 64;

    int rr  = lane >> 3;
    int sl  = lane & 7;
    int gsw = (sl - rr) & 7;

    if (tid < 32) {                          // epilogue index stash
        int g = m0 + tid;
        int b = g >> 9;                      // R = 512
        hI[tid]  = b * V_ + ht[2 * g];
        tI[tid]  = b * V_ + ht[2 * g + 1];
        dhI[tid] = dht[g];
        dtI[tid] = dth[g];
    }

    int hoff[2], toff[2];
#pragma unroll
    for (int gi = 0; gi < 2; ++gi) {
        int g = m0 + wv * 16 + gi * 8 + rr;
        int b = g >> 9;
        hoff[gi] = (b * V_ + ht[2 * g])     * KD_;
        toff[gi] = (b * V_ + ht[2 * g + 1]) * KD_;
    }

    auto stage = [&](int bf, int it) {
        int kk = it * 64 + gsw * 8;
#pragma unroll
        for (int gi = 0; gi < 2; ++gi) {
            bf16x8 h = *(const bf16x8*)(vembB + hoff[gi] + kk);
            bf16x8 t = *(const bf16x8*)(vembB + toff[gi] + kk);
            bf16x8 p;
#pragma unroll
            for (int j = 0; j < 8; ++j) p[j] = f2bf(bf2f(h[j]) * bf2f(t[j]));
            *(bf16x8*)&Abuf[bf][wv * 16 + gi * 8 + rr][sl * 8] = p;
        }
        const ushort_t* bbase = W1P + ((size_t)it * 6 + nt) * 4096;
#pragma unroll
        for (int q = 0; q < 4; ++q) {
            int p = wv * 4 + q;
            dma16(bbase + (size_t)p * 512 + lane * 8, &Bbuf[bf][p][0][0]);
        }
    };

    int half = lane >> 5;
    int lrow = lane & 31;
    int wn   = wv * 32;

    f32x16 acc;
#pragma unroll
    for (int r = 0; r < 16; ++r) acc[r] = 0.f;

    stage(0, 0);
    for (int it = 0; it < 12; ++it) {
        int bf = it & 1;
        __syncthreads();                     // drains DMA + ds_writes + reads
        if (it + 1 < 12) stage(bf ^ 1, it + 1);
#pragma unroll
        for (int s = 0; s < 4; ++s) {
            int kg   = s * 2 + half;
            int slot = ((kg + lrow) & 7) * 8;
            bf16x8 a = *(bf16x8*)&Abuf[bf][lrow][slot];
            bf16x8 b = *(bf16x8*)&Bbuf[bf][kg][wn + lrow][0];
            acc = __builtin_amdgcn_mfma_f32_32x32x16_bf16(a, b, acc, 0, 0, 0);
        }
    }

    int col = n0 + wn + lrow;
#pragma unroll
    for (int r = 0; r < 16; ++r) {
        int rl = (r & 3) + 8 * (r >> 2) + 4 * half;        // local row 0..31
        float v = acc[r]
                + vproj[(size_t)hI[rl] * KD_ + col]
                + vproj[(size_t)tI[rl] * KD_ + HID_ + col]
                + disH[dhI[rl] * HID_ + col]
                + disT[dtI[rl] * HID_ + col];
        hidden[(size_t)(m0 + rl) * HID_ + col] = (ushort_t)f2bf(fmaxf(v, 0.f));
    }
}

// ---------------------------------------------------------------------------
// Kernel 5: MFMA GEMM2 + bias (verbatim verified).
// ---------------------------------------------------------------------------
__global__ __launch_bounds__(256) void gemm2_kernel(
    const ushort_t* __restrict__ hidden, const ushort_t* __restrict__ W2T,
    const float* __restrict__ b2, float* __restrict__ out)
{
    __shared__ ushort_t As[32][72];
    __shared__ ushort_t Bs[128][72];

    int m0  = blockIdx.x * 32;
    int tid = threadIdx.x;

    int arow = tid >> 3;             // 0..31
    int akk  = (tid & 7) * 8;

    bf16x8 pA; bf16x8 pB[4];
    auto loadAB = [&](int k0) {
        pA = *(const bf16x8*)(hidden + (size_t)(m0 + arow) * HID_ + k0 + akk);
#pragma unroll
        for (int e = 0; e < 4; ++e)
            pB[e] = *(const bf16x8*)(W2T + (size_t)(arow + e * 32) * HID_ + k0 + akk);
    };

    int w    = tid >> 6;
    int lane = tid & 63;
    int wm = (w & 1) * 16;
    int wn = (w >> 1) * 64;
    int lr = lane & 15, lq = lane >> 4;

    f32x4 acc[4];
#pragma unroll
    for (int e = 0; e < 4; ++e) acc[e] = (f32x4){0.f, 0.f, 0.f, 0.f};

    loadAB(0);
    for (int k0 = 0; k0 < HID_; k0 += 64) {
        __syncthreads();
        *(bf16x8*)&As[arow][akk] = pA;
#pragma unroll
        for (int e = 0; e < 4; ++e)
            *(bf16x8*)&Bs[arow + e * 32][akk] = pB[e];
        __syncthreads();
        if (k0 + 64 < HID_) loadAB(k0 + 64);
#pragma unroll
        for (int ks = 0; ks < 2; ++ks) {
            int kb = ks * 32 + lq * 8;
            bf16x8 a = *(bf16x8*)&As[wm + lr][kb];
#pragma unroll
            for (int nf = 0; nf < 4; ++nf) {
                bf16x8 bb = *(bf16x8*)&Bs[wn + nf * 16 + lr][kb];
                acc[nf] = __builtin_amdgcn_mfma_f32_16x16x32_bf16(a, bb, acc[nf], 0, 0, 0);
            }
        }
    }

    int grow = m0 + wm + lq * 4;
#pragma unroll
    for (int nf = 0; nf < 4; ++nf) {
        int col = wn + nf * 16 + lr;
        if (col < REL_) {
            float bias = b2[col];
#pragma unroll
            for (int r = 0; r < 4; ++r)
                out[(size_t)(grow + r) * REL_ + col] = acc[nf][r] + bias;
        }
    }
}

// ---------------------------------------------------------------------------
extern "C" void kernel_launch(void* const* d_in, const int* in_sizes, int n_in,
                              void* d_out, int out_size, void* d_ws, size_t ws_size,
                              hipStream_t stream)
{
    const float* sr    = (const float*)d_in[0];
    const int*   spans = (const int*)  d_in[1];
    const int*   vidx  = (const int*)  d_in[3];
    const int*   vmask = (const int*)  d_in[4];
    const int*   ht    = (const int*)  d_in[5];
    const int*   dht   = (const int*)  d_in[7];
    const int*   dth   = (const int*)  d_in[8];
    const float* dis   = (const float*)d_in[9];
    const float* W1    = (const float*)d_in[10];
    const float* W2    = (const float*)d_in[11];
    const float* b2    = (const float*)d_in[12];
    float* out = (float*)d_out;

    // ws layout (bf16 regions first, then f32):
    ushort_t* span_emb = (ushort_t*)d_ws;                     // 4096*768
    ushort_t* vembB    = span_emb + (size_t)B_ * NS_ * D_;    // 2048*768
    ushort_t* W1HT     = vembB + (size_t)B_ * V_ * D_;        // 144*4096
    ushort_t* W1P      = W1HT + (size_t)144 * 4096;           // 72*4096
    ushort_t* W2T      = W1P + (size_t)72 * 4096;             // 128*384
    ushort_t* hidden   = W2T + (size_t)N2P_ * HID_;           // 8192*384
    float* vproj = (float*)(hidden + (size_t)B_ * R_ * HID_); // 2048*768 f32
    float* disH  = vproj + (size_t)B_ * V_ * KD_;             // 20*384 f32
    float* disT  = disH + (size_t)DIS_ * HID_;                // 20*384 f32

    prep_kernel<<<4784, 192, 0, stream>>>(
        sr, spans, W1, W2, dis, span_emb, W1HT, W1P, W2T, disH, disT);
    vertex_kernel<<<B_ * V_, 192, 0, stream>>>(span_emb, vidx, vmask, vembB);
    gemmc_kernel<<<dim3(64, 12), 256 / 2, 0, stream>>>(vembB, W1HT, vproj);
    gemmd_kernel<<<dim3(256, 6), 128, 0, stream>>>(
        vembB, ht, dht, dth, W1P, vproj, disH, disT, hidden);
    gemm2_kernel<<<(B_ * R_) / 32, 256, 0, stream>>>(hidden, W2T, b2, out);
}

// Round 9
// 149.640 us; speedup vs baseline: 1.0589x; 1.0227x over previous
//
#include <hip/hip_runtime.h>
#include <cstdint>
#include <cstddef>

// Problem constants
#define B_    16
#define S_    1024
#define D_    768
#define NS_   256
#define V_    128
#define C_    6
#define R_    512
#define REL_  97
#define HID_  384
#define DIS_  20
#define KD_   768    // K for both hoisted GEMMs (= D_)
#define N2P_  128    // gemm2 padded N

typedef unsigned short ushort_t;
typedef unsigned int   u32;
typedef short bf16x4 __attribute__((ext_vector_type(4)));
typedef short bf16x8 __attribute__((ext_vector_type(8)));
typedef float f32x4  __attribute__((ext_vector_type(4)));
typedef float f32x16 __attribute__((ext_vector_type(16)));

__device__ __forceinline__ float bf2f(short s) {
    return __uint_as_float(((unsigned int)(unsigned short)s) << 16);
}
__device__ __forceinline__ short f2bf(float x) {   // RNE
    union { float f; unsigned int u; } c; c.f = x;
    unsigned int r = (c.u + 0x7fffu + ((c.u >> 16) & 1u)) >> 16;
    return (short)(unsigned short)r;
}

// async global->LDS, 16 B per lane; LDS dest = wave-uniform base + lane*16
typedef const __attribute__((address_space(1))) u32* gas_t;
typedef __attribute__((address_space(3))) u32*       las_t;
__device__ __forceinline__ void dma16(const void* g, void* l) {
    __builtin_amdgcn_global_load_lds((gas_t)g, (las_t)l, 16, 0, 0);
}

// ---------------------------------------------------------------------------
// Kernel 1 (prep), 192 threads: span max-pool, W1/W2 repacks, dis tables.
// (verbatim R3-verified)
// ---------------------------------------------------------------------------
__global__ __launch_bounds__(192) void prep_kernel(
    const float* __restrict__ sr, const int* __restrict__ spans,
    const float* __restrict__ W1, const float* __restrict__ W2,
    const float* __restrict__ dis,
    ushort_t* __restrict__ span_emb, ushort_t* __restrict__ W1HT,
    ushort_t* __restrict__ W1P, ushort_t* __restrict__ W2T,
    float* __restrict__ disH, float* __restrict__ disT)
{
    int blk = blockIdx.x;
    int tid = threadIdx.x;
    if (blk < 4096) {
        int bn    = blk;
        int b     = bn >> 8;                 // NS = 256
        int start = spans[2 * bn];
        int end   = spans[2 * bn + 1];
        int w     = end - start;             // 0..7, block-uniform
        const float* base = sr + ((size_t)b * S_ + start) * D_ + tid * 4;
        f32x4 x[8];
        x[0] = *(const f32x4*)base;
        switch (w) {                         // block-uniform fallthrough
        case 7: x[7] = *(const f32x4*)(base + 7 * D_); [[fallthrough]];
        case 6: x[6] = *(const f32x4*)(base + 6 * D_); [[fallthrough]];
        case 5: x[5] = *(const f32x4*)(base + 5 * D_); [[fallthrough]];
        case 4: x[4] = *(const f32x4*)(base + 4 * D_); [[fallthrough]];
        case 3: x[3] = *(const f32x4*)(base + 3 * D_); [[fallthrough]];
        case 2: x[2] = *(const f32x4*)(base + 2 * D_); [[fallthrough]];
        case 1: x[1] = *(const f32x4*)(base + 1 * D_); break;
        default: break;
        }
        f32x4 m = x[0];
#pragma unroll
        for (int j = 1; j < 8; ++j)
            if (j <= w) {
#pragma unroll
                for (int c = 0; c < 4; ++c) m[c] = fmaxf(m[c], x[j][c]);
            }
        bf16x4 o;
#pragma unroll
        for (int c = 0; c < 4; ++c) o[c] = f2bf(m[c]);
        *(bf16x4*)(span_emb + (size_t)bn * D_ + tid * 4) = o;
    } else if (blk < 4480) {                 // W1HT: 384 blocks
        int flat = (blk - 4096) * 192 + tid;
        int nn   = flat & 63;
        int kg   = (flat >> 6) & 7;
        int itnt = flat >> 9;                // it*12 + nt, 0..143
        int it   = itnt / 12;
        int nt   = itnt - it * 12;
        bf16x8 p;
#pragma unroll
        for (int j = 0; j < 8; ++j) {
            int k = it * 64 + kg * 8 + j;
            int n = nt * 64 + nn;
            float v = (n < HID_) ? W1[(size_t)k * HID_ + n]
                                 : W1[(size_t)(788 + k) * HID_ + (n - HID_)];
            p[j] = f2bf(v);
        }
        *(bf16x8*)(W1HT + ((size_t)itnt * 8 + kg) * 512 + nn * 8) = p;
    } else if (blk < 4672) {                 // W1P: 192 blocks
        int flat = (blk - 4480) * 192 + tid;
        int nn   = flat & 63;
        int kg   = (flat >> 6) & 7;
        int itnt = flat >> 9;                // it*6 + nt, 0..71
        int it   = itnt / 6;
        int nt   = itnt - it * 6;
        bf16x8 p;
#pragma unroll
        for (int j = 0; j < 8; ++j) {
            int k = it * 64 + kg * 8 + j;
            int n = nt * 64 + nn;
            p[j] = f2bf(W1[(size_t)(1576 + k) * HID_ + n]);
        }
        *(bf16x8*)(W1P + ((size_t)itnt * 8 + kg) * 512 + nn * 8) = p;
    } else if (blk < 4704) {                 // W2T: 32 blocks
        int g  = (blk - 4672) * 192 + tid;   // 0..6143
        int n  = g / 48;
        int k0 = (g - n * 48) * 8;
        bf16x8 p;
#pragma unroll
        for (int j = 0; j < 8; ++j) {
            float v = (n < REL_) ? W2[(size_t)(k0 + j) * REL_ + n] : 0.f;
            p[j] = f2bf(v);
        }
        *(bf16x8*)(W2T + (size_t)n * HID_ + k0) = p;
    } else {                                 // dis tables: 80 blocks
        int g   = (blk - 4704) * 192 + tid;
        int sel = g >= 7680;
        int gg  = sel ? g - 7680 : g;
        int i   = gg / HID_;
        int n   = gg - i * HID_;
        int rb  = sel ? 1556 : 768;
        float a = 0.f;
#pragma unroll
        for (int j = 0; j < DIS_; ++j)
            a += dis[i * DIS_ + j] * W1[(size_t)(rb + j) * HID_ + n];
        (sel ? disT : disH)[i * HID_ + n] = a;
    }
}

// ---------------------------------------------------------------------------
// Kernel 2: vertex mean (verbatim R3-verified).
// ---------------------------------------------------------------------------
__global__ __launch_bounds__(192) void vertex_kernel(
    const ushort_t* __restrict__ span_emb, const int* __restrict__ vidx,
    const int* __restrict__ vmask, ushort_t* __restrict__ vembB)
{
    int bv = blockIdx.x;
    int b  = bv >> 7;                // V = 128
    const int* vi = vidx  + bv * C_;
    const int* vm = vmask + bv * C_;
    int   idxs[C_];
    float ms[C_];
    float cnt = 0.f;
#pragma unroll
    for (int c = 0; c < C_; ++c) {
        idxs[c] = vi[c];
        ms[c]   = (float)vm[c];
        cnt    += ms[c];
    }
    float inv = 1.f / fmaxf(cnt, 1.f);
    int col = threadIdx.x * 4;
    float s[4] = {0.f, 0.f, 0.f, 0.f};
#pragma unroll
    for (int c = 0; c < C_; ++c) {
        if (ms[c] != 0.f) {
            bf16x4 x = *(const bf16x4*)(span_emb +
                        ((size_t)(b * NS_ + idxs[c])) * D_ + col);
#pragma unroll
            for (int q = 0; q < 4; ++q) s[q] += bf2f(x[q]);
        }
    }
    bf16x4 o;
#pragma unroll
    for (int q = 0; q < 4; ++q) o[q] = f2bf(s[q] * inv);
    *(bf16x4*)(vembB + (size_t)bv * D_ + col) = o;
}

// ---------------------------------------------------------------------------
// Kernel 3 (GEMM C, R8-verified tiling): vproj = vembB @ W1HT, f32 out.
// BM=32 x BN=64, 128 threads (2 waves), 24 KB LDS -> 6 blocks/CU.
// Grid 64 x 12 = 768 blocks -> all 256 CUs occupied (R3's 384-block version
// left half the GPU idle).
// ---------------------------------------------------------------------------
__global__ __launch_bounds__(128, 3) void gemmc_kernel(
    const ushort_t* __restrict__ vembB, const ushort_t* __restrict__ W1HT,
    float* __restrict__ vproj)
{
    __shared__ ushort_t Abuf[2][32][64];     // 8 KB (swizzled slots)
    __shared__ ushort_t Bbuf[2][8][64][8];   // 16 KB (granule planes)

    int tid  = threadIdx.x;
    int wv   = tid >> 6;                     // 0..1
    int lane = tid & 63;
    int m0   = blockIdx.x * 32;
    int nt   = blockIdx.y;                   // 0..11
    int n0   = nt * 64;

    int rr  = lane >> 3;
    int sl  = lane & 7;
    int gsw = (sl - rr) & 7;

    const ushort_t* asrc[2];
#pragma unroll
    for (int gi = 0; gi < 2; ++gi)
        asrc[gi] = vembB + (size_t)(m0 + wv * 16 + gi * 8 + rr) * KD_ + gsw * 8;

    auto stage = [&](int bf, int it) {
#pragma unroll
        for (int gi = 0; gi < 2; ++gi)
            dma16(asrc[gi] + it * 64, &Abuf[bf][wv * 16 + gi * 8][0]);
        const ushort_t* bbase = W1HT + ((size_t)it * 12 + nt) * 4096;
#pragma unroll
        for (int q = 0; q < 4; ++q) {
            int p = wv * 4 + q;
            dma16(bbase + (size_t)p * 512 + lane * 8, &Bbuf[bf][p][0][0]);
        }
    };

    int half = lane >> 5;
    int lrow = lane & 31;
    int wn   = wv * 32;

    f32x16 acc;
#pragma unroll
    for (int r = 0; r < 16; ++r) acc[r] = 0.f;

    stage(0, 0);
    for (int it = 0; it < 12; ++it) {
        int bf = it & 1;
        __syncthreads();
        if (it + 1 < 12) stage(bf ^ 1, it + 1);
#pragma unroll
        for (int s = 0; s < 4; ++s) {
            int kg   = s * 2 + half;
            int slot = ((kg + lrow) & 7) * 8;
            bf16x8 a = *(bf16x8*)&Abuf[bf][lrow][slot];
            bf16x8 b = *(bf16x8*)&Bbuf[bf][kg][wn + lrow][0];
            acc = __builtin_amdgcn_mfma_f32_32x32x16_bf16(a, b, acc, 0, 0, 0);
        }
    }

    // C/D 32x32 layout: col=lane&31, row=(reg&3)+8*(reg>>2)+4*(lane>>5)
    int col = n0 + wn + lrow;
#pragma unroll
    for (int r = 0; r < 16; ++r) {
        int row = m0 + (r & 3) + 8 * (r >> 2) + 4 * half;
        vproj[(size_t)row * KD_ + col] = acc[r];
    }
}

// ---------------------------------------------------------------------------
// Kernel 4 (GEMM D): pair-product GEMM + additive epilogue.
// (verbatim R3-verified: BM=64 x BN=64, 256 threads, grid 128x6, 3/CU —
//  the low-B-traffic shape; R6/R8 variants both regressed.)
// ---------------------------------------------------------------------------
__global__ __launch_bounds__(256, 3) void gemmd_kernel(
    const ushort_t* __restrict__ vembB, const int* __restrict__ ht,
    const int* __restrict__ dht, const int* __restrict__ dth,
    const ushort_t* __restrict__ W1P, const float* __restrict__ vproj,
    const float* __restrict__ disH, const float* __restrict__ disT,
    ushort_t* __restrict__ hidden)
{
    __shared__ ushort_t Abuf[2][64][64];
    __shared__ ushort_t Bbuf[2][8][64][8];
    __shared__ int hI[64], tI[64], dhI[64], dtI[64];

    int tid  = threadIdx.x;
    int wv   = tid >> 6;
    int lane = tid & 63;
    int m0   = blockIdx.x * 64;
    int nt   = blockIdx.y;
    int n0   = nt * 64;

    int rr  = lane >> 3;
    int sl  = lane & 7;
    int gsw = (sl - rr) & 7;

    if (tid < 64) {
        int g = m0 + tid;
        int b = g >> 9;                      // R = 512
        hI[tid]  = b * V_ + ht[2 * g];
        tI[tid]  = b * V_ + ht[2 * g + 1];
        dhI[tid] = dht[g];
        dtI[tid] = dth[g];
    }

    int hoff[2], toff[2];
#pragma unroll
    for (int gi = 0; gi < 2; ++gi) {
        int g = m0 + wv * 16 + gi * 8 + rr;
        int b = g >> 9;
        hoff[gi] = (b * V_ + ht[2 * g])     * KD_;
        toff[gi] = (b * V_ + ht[2 * g + 1]) * KD_;
    }

    auto stage = [&](int bf, int it) {
        int kk = it * 64 + gsw * 8;
#pragma unroll
        for (int gi = 0; gi < 2; ++gi) {
            bf16x8 h = *(const bf16x8*)(vembB + hoff[gi] + kk);
            bf16x8 t = *(const bf16x8*)(vembB + toff[gi] + kk);
            bf16x8 p;
#pragma unroll
            for (int j = 0; j < 8; ++j) p[j] = f2bf(bf2f(h[j]) * bf2f(t[j]));
            *(bf16x8*)&Abuf[bf][wv * 16 + gi * 8 + rr][sl * 8] = p;
        }
        const ushort_t* bbase = W1P + ((size_t)it * 6 + nt) * 4096;
#pragma unroll
        for (int q = 0; q < 2; ++q) {
            int p = wv * 2 + q;
            dma16(bbase + (size_t)p * 512 + lane * 8, &Bbuf[bf][p][0][0]);
        }
    };

    int half = lane >> 5;
    int lrow = lane & 31;
    int wm   = (wv & 1) * 32;
    int wn   = (wv >> 1) * 32;

    f32x16 acc;
#pragma unroll
    for (int r = 0; r < 16; ++r) acc[r] = 0.f;

    stage(0, 0);
    for (int it = 0; it < 12; ++it) {
        int bf = it & 1;
        __syncthreads();
        if (it + 1 < 12) stage(bf ^ 1, it + 1);
#pragma unroll
        for (int s = 0; s < 4; ++s) {
            int kg   = s * 2 + half;
            int slot = ((kg + lrow) & 7) * 8;
            bf16x8 a = *(bf16x8*)&Abuf[bf][wm + lrow][slot];
            bf16x8 b = *(bf16x8*)&Bbuf[bf][kg][wn + lrow][0];
            acc = __builtin_amdgcn_mfma_f32_32x32x16_bf16(a, b, acc, 0, 0, 0);
        }
    }

    int col = n0 + wn + lrow;
#pragma unroll
    for (int r = 0; r < 16; ++r) {
        int rl = wm + (r & 3) + 8 * (r >> 2) + 4 * half;
        float v = acc[r]
                + vproj[(size_t)hI[rl] * KD_ + col]
                + vproj[(size_t)tI[rl] * KD_ + HID_ + col]
                + disH[dhI[rl] * HID_ + col]
                + disT[dtI[rl] * HID_ + col];
        hidden[(size_t)(m0 + rl) * HID_ + col] = (ushort_t)f2bf(fmaxf(v, 0.f));
    }
}

// ---------------------------------------------------------------------------
// Kernel 5: MFMA GEMM2 + bias (verbatim verified).
// ---------------------------------------------------------------------------
__global__ __launch_bounds__(256) void gemm2_kernel(
    const ushort_t* __restrict__ hidden, const ushort_t* __restrict__ W2T,
    const float* __restrict__ b2, float* __restrict__ out)
{
    __shared__ ushort_t As[32][72];
    __shared__ ushort_t Bs[128][72];

    int m0  = blockIdx.x * 32;
    int tid = threadIdx.x;

    int arow = tid >> 3;             // 0..31
    int akk  = (tid & 7) * 8;

    bf16x8 pA; bf16x8 pB[4];
    auto loadAB = [&](int k0) {
        pA = *(const bf16x8*)(hidden + (size_t)(m0 + arow) * HID_ + k0 + akk);
#pragma unroll
        for (int e = 0; e < 4; ++e)
            pB[e] = *(const bf16x8*)(W2T + (size_t)(arow + e * 32) * HID_ + k0 + akk);
    };

    int w    = tid >> 6;
    int lane = tid & 63;
    int wm = (w & 1) * 16;
    int wn = (w >> 1) * 64;
    int lr = lane & 15, lq = lane >> 4;

    f32x4 acc[4];
#pragma unroll
    for (int e = 0; e < 4; ++e) acc[e] = (f32x4){0.f, 0.f, 0.f, 0.f};

    loadAB(0);
    for (int k0 = 0; k0 < HID_; k0 += 64) {
        __syncthreads();
        *(bf16x8*)&As[arow][akk] = pA;
#pragma unroll
        for (int e = 0; e < 4; ++e)
            *(bf16x8*)&Bs[arow + e * 32][akk] = pB[e];
        __syncthreads();
        if (k0 + 64 < HID_) loadAB(k0 + 64);
#pragma unroll
        for (int ks = 0; ks < 2; ++ks) {
            int kb = ks * 32 + lq * 8;
            bf16x8 a = *(bf16x8*)&As[wm + lr][kb];
#pragma unroll
            for (int nf = 0; nf < 4; ++nf) {
                bf16x8 bb = *(bf16x8*)&Bs[wn + nf * 16 + lr][kb];
                acc[nf] = __builtin_amdgcn_mfma_f32_16x16x32_bf16(a, bb, acc[nf], 0, 0, 0);
            }
        }
    }

    int grow = m0 + wm + lq * 4;
#pragma unroll
    for (int nf = 0; nf < 4; ++nf) {
        int col = wn + nf * 16 + lr;
        if (col < REL_) {
            float bias = b2[col];
#pragma unroll
            for (int r = 0; r < 4; ++r)
                out[(size_t)(grow + r) * REL_ + col] = acc[nf][r] + bias;
        }
    }
}

// ---------------------------------------------------------------------------
extern "C" void kernel_launch(void* const* d_in, const int* in_sizes, int n_in,
                              void* d_out, int out_size, void* d_ws, size_t ws_size,
                              hipStream_t stream)
{
    const float* sr    = (const float*)d_in[0];
    const int*   spans = (const int*)  d_in[1];
    const int*   vidx  = (const int*)  d_in[3];
    const int*   vmask = (const int*)  d_in[4];
    const int*   ht    = (const int*)  d_in[5];
    const int*   dht   = (const int*)  d_in[7];
    const int*   dth   = (const int*)  d_in[8];
    const float* dis   = (const float*)d_in[9];
    const float* W1    = (const float*)d_in[10];
    const float* W2    = (const float*)d_in[11];
    const float* b2    = (const float*)d_in[12];
    float* out = (float*)d_out;

    // ws layout (bf16 regions first, then f32):
    ushort_t* span_emb = (ushort_t*)d_ws;                     // 4096*768
    ushort_t* vembB    = span_emb + (size_t)B_ * NS_ * D_;    // 2048*768
    ushort_t* W1HT     = vembB + (size_t)B_ * V_ * D_;        // 144*4096
    ushort_t* W1P      = W1HT + (size_t)144 * 4096;           // 72*4096
    ushort_t* W2T      = W1P + (size_t)72 * 4096;             // 128*384
    ushort_t* hidden   = W2T + (size_t)N2P_ * HID_;           // 8192*384
    float* vproj = (float*)(hidden + (size_t)B_ * R_ * HID_); // 2048*768 f32
    float* disH  = vproj + (size_t)B_ * V_ * KD_;             // 20*384 f32
    float* disT  = disH + (size_t)DIS_ * HID_;                // 20*384 f32

    prep_kernel<<<4784, 192, 0, stream>>>(
        sr, spans, W1, W2, dis, span_emb, W1HT, W1P, W2T, disH, disT);
    vertex_kernel<<<B_ * V_, 192, 0, stream>>>(span_emb, vidx, vmask, vembB);
    gemmc_kernel<<<dim3(64, 12), 128, 0, stream>>>(vembB, W1HT, vproj);
    gemmd_kernel<<<dim3(128, 6), 256, 0, stream>>>(
        vembB, ht, dht, dth, W1P, vproj, disH, disT, hidden);
    gemm2_kernel<<<(B_ * R_) / 32, 256, 0, stream>>>(hidden, W2T, b2, out);
}